// Round 22
// baseline (22.386 us; speedup 1.0000x reference)
//
#include <hip/hip_runtime.h>

// RuleNet: out[b] = 5 + sum_c rw[c] * min_j( mu[c,j]*x[b,j] + (1-mu[c,j]) )
// x = [x0, 1-x0], mu = sigmoid(conjunctions).
// fit(b,c) = 1 - max_v max( mu1*(1-x0), mu2*x0 ).
//
// R22 = R21 (hand-lowered v_pk_mul_f16/v_pk_max_f16 core — the _Float16
// builtins mislower, R19/R20) stretched to 4 c/lane (NCH=2): same 8 x-LDS
// reads per QSTEP now feed 256 pk instrs (32 pk/read vs 16). GPU-wide
// x-LDS reads halve; total instructions -10%. 256 blocks, 1/CU, 8 waves,
// barrier-free main loop. Two-round epilogue (cA/cB then cC/cD).

#define B_    1024
#define C_    512
#define V_    256
#define TWOV  512

#define BPB    8               // batches per block
#define NBG    (B_ / BPB)      // 128 b-groups
#define NCH    2               // 2 chunks of 256 c (4 per lane)

typedef float    f32x4 __attribute__((ext_vector_type(4)));
typedef _Float16 h16x2 __attribute__((ext_vector_type(2)));

__device__ __forceinline__ float sigf(float z) {
    return 1.0f / (1.0f + __expf(-z));
}
__device__ __forceinline__ float packh2(float a, float b) {
    h16x2 h; h.x = (_Float16)a; h.y = (_Float16)b;
    return __builtin_bit_cast(float, h);
}

// packed f16 ops, hand-lowered (32-bit float carriers)
#define PKMUL(D, A, Bq) asm("v_pk_mul_f16 %0, %1, %2" : "=v"(D) : "v"(A), "v"(Bq))
#define PKMAX(ACC, T)   asm("v_pk_max_f16 %0, %0, %1" : "+v"(ACC) : "v"(T))

// ---------- kernel 1: sigmoid -> f16 pack, + out=5.0 init ----------
// muH[vq][c] : 16B = { m1(v0,v1), m1(v2,v3), m2(v0,v1), m2(v2,v3) } as f16 pairs
__global__ __launch_bounds__(512) void k_prep(const float* __restrict__ conj,
                                              float4* __restrict__ muH,
                                              float* __restrict__ out) {
    const int vq = blockIdx.x;       // 64 blocks = v-quads
    const int c  = threadIdx.x;      // 512 threads = conjunctions
    if (vq < 2) out[vq * 512 + c] = 5.0f;
    const float* row = conj + (size_t)c * TWOV;
    const int v = vq * 4;
    float4 r;
    r.x = packh2(sigf(row[v + 0]),      sigf(row[v + 1]));
    r.y = packh2(sigf(row[v + 2]),      sigf(row[v + 3]));
    r.z = packh2(sigf(row[V_ + v + 0]), sigf(row[V_ + v + 1]));
    r.w = packh2(sigf(row[V_ + v + 2]), sigf(row[V_ + v + 3]));
    muH[(size_t)vq * C_ + c] = r;    // coalesced 512 x 16B
}

// ---------- kernel 2: main fuzzy-AND (packed f16, 4 c/lane) ----------
__global__ __launch_bounds__(512, 2) void k_main(const float* __restrict__ x0,
                                                 const float4* __restrict__ muH,
                                                 const float* __restrict__ rw,
                                                 float* __restrict__ out) {
    const int tid  = threadIdx.x;
    const int lane = tid & 63;
    const int wave = tid >> 6;                   // v-eighth owner (32 v = 8 vq)
    const int bg   = blockIdx.x;                 // 128 groups of 8 batches
    const int chunk= blockIdx.y;                 // 2 chunks of 256 c
    const int cA   = chunk * 256 + lane;         // lane's c's: cA,+64,+128,+192
    const int vq0  = wave * 8;                   // this wave's vq base

    __shared__ float4 xs4[BPB * 64];             // 8 KB: [b][vq] {x01,x23,c01,c23}
    __shared__ float  red[8 * 64 * 17];          // 34 KB epilogue (stride 17)

    // stage x as f16 (x, 1-x) pairs; thread -> (b = tid>>6, vq = tid&63)
    {
        const int b = tid >> 6, vq = tid & 63;
        float4 xv = *reinterpret_cast<const float4*>(
            x0 + (size_t)(bg * BPB + b) * V_ + vq * 4);
        float4 pk;
        pk.x = packh2(xv.x, xv.y);               // x      (v0,v1)
        pk.y = packh2(xv.z, xv.w);               // x      (v2,v3)
        pk.z = packh2(1.0f - xv.x, 1.0f - xv.y); // (1-x)  (v0,v1)
        pk.w = packh2(1.0f - xv.z, 1.0f - xv.w); // (1-x)  (v2,v3)
        xs4[tid] = pk;
    }

    const float4* p = muH + (size_t)vq0 * C_ + cA;   // row q at p[q*C_]

    float accA[BPB], accB[BPB], accC[BPB], accD[BPB];   // f16x2 carriers
#pragma unroll
    for (int i = 0; i < BPB; ++i) {
        accA[i] = 0.0f; accB[i] = 0.0f; accC[i] = 0.0f; accD[i] = 0.0f;
    }

    // prologue loads (compiler-visible; offsets 0/1024/2048/3072 fold)
    float4 MA = p[0];
    float4 MB = p[64];
    float4 MC = p[128];
    float4 MD = p[192];

    __syncthreads();                             // x tile ready

    // one c's worth: 4 pk_mul + 4 pk_max into ACC
#define CPIECE(XC, M, ACC) do { \
    float t0, t1, t2, t3; \
    PKMUL(t0, M.x, XC.z);   /* m1(v0,v1) * (1-x)(v0,v1) */ \
    PKMUL(t1, M.z, XC.x);   /* m2(v0,v1) * x(v0,v1)     */ \
    PKMUL(t2, M.y, XC.w);   /* m1(v2,v3) * (1-x)(v2,v3) */ \
    PKMUL(t3, M.w, XC.y);   /* m2(v2,v3) * x(v2,v3)     */ \
    PKMAX(ACC, t0); PKMAX(ACC, t1); PKMAX(ACC, t2); PKMAX(ACC, t3); \
    } while (0)

#define PAIR4(XC, bi) do { \
    CPIECE(XC, MA, accA[bi]); \
    CPIECE(XC, MB, accB[bi]); \
    CPIECE(XC, MC, accC[bi]); \
    CPIECE(XC, MD, accD[bi]); \
    } while (0)

#pragma unroll
    for (int q = 0; q < 8; ++q) {
        // batch the 8 x ds_reads (independent, in flight together)
        float4 xc0 = xs4[0 * 64 + vq0 + q];
        float4 xc1 = xs4[1 * 64 + vq0 + q];
        float4 xc2 = xs4[2 * 64 + vq0 + q];
        float4 xc3 = xs4[3 * 64 + vq0 + q];
        float4 xc4 = xs4[4 * 64 + vq0 + q];
        float4 xc5 = xs4[5 * 64 + vq0 + q];
        float4 xc6 = xs4[6 * 64 + vq0 + q];
        float4 xc7 = xs4[7 * 64 + vq0 + q];
        // depth-1 prefetch of next row (compiler-visible)
        float4 NA, NB, NC, ND;
        if (q < 7) {
            NA = p[(size_t)(q + 1) * C_];
            NB = p[(size_t)(q + 1) * C_ + 64];
            NC = p[(size_t)(q + 1) * C_ + 128];
            ND = p[(size_t)(q + 1) * C_ + 192];
        }
        // pin current AFTER next's issue (R8-validated component pin)
        asm volatile("" : "+v"(MA.x), "+v"(MA.y), "+v"(MA.z), "+v"(MA.w),
                          "+v"(MB.x), "+v"(MB.y), "+v"(MB.z), "+v"(MB.w),
                          "+v"(MC.x), "+v"(MC.y), "+v"(MC.z), "+v"(MC.w),
                          "+v"(MD.x), "+v"(MD.y), "+v"(MD.z), "+v"(MD.w));
        PAIR4(xc0, 0);
        PAIR4(xc1, 1);
        PAIR4(xc2, 2);
        PAIR4(xc3, 3);
        PAIR4(xc4, 4);
        PAIR4(xc5, 5);
        PAIR4(xc6, 6);
        PAIR4(xc7, 7);
        if (q < 7) { MA = NA; MB = NB; MC = NC; MD = ND; }
    }
#undef PAIR4
#undef CPIECE

    // fold packed accumulators to f32 scalars
    float mA[BPB], mB[BPB], mC[BPB], mD[BPB];
#pragma unroll
    for (int bi = 0; bi < BPB; ++bi) {
        h16x2 ha = __builtin_bit_cast(h16x2, accA[bi]);
        h16x2 hb = __builtin_bit_cast(h16x2, accB[bi]);
        h16x2 hc = __builtin_bit_cast(h16x2, accC[bi]);
        h16x2 hd = __builtin_bit_cast(h16x2, accD[bi]);
        mA[bi] = fmaxf((float)ha.x, (float)ha.y);
        mB[bi] = fmaxf((float)hb.x, (float)hb.y);
        mC[bi] = fmaxf((float)hc.x, (float)hc.y);
        mD[bi] = fmaxf((float)hd.x, (float)hd.y);
    }

    // ---- epilogue: two rounds (cA/cB then cC/cD) ----
#define FINROUND(MLO, MHI, COFF) do { \
    _Pragma("unroll") \
    for (int bi = 0; bi < BPB; ++bi) { \
        red[(wave * 64 + lane) * 17 + bi * 2 + 0] = MLO[bi]; \
        red[(wave * 64 + lane) * 17 + bi * 2 + 1] = MHI[bi]; \
    } \
    __syncthreads(); \
    if (wave < 2) { \
        const float rwc = rw[chunk * 256 + (COFF) + wave * 64 + lane]; \
        float con0, con1, con2, con3, con4, con5, con6, con7; \
        FIN(0, con0); FIN(1, con1); FIN(2, con2); FIN(3, con3); \
        FIN(4, con4); FIN(5, con5); FIN(6, con6); FIN(7, con7); \
        float t0 = (lane & 1) ? con1 : con0; \
        float t1 = (lane & 1) ? con3 : con2; \
        float t2 = (lane & 1) ? con5 : con4; \
        float t3 = (lane & 1) ? con7 : con6; \
        float u0 = (lane & 2) ? t1 : t0; \
        float u1 = (lane & 2) ? t3 : t2; \
        float sel = (lane & 4) ? u1 : u0; \
        if (lane < 8) \
            atomicAdd(&out[bg * BPB + lane], sel); \
    } \
    __syncthreads(); \
    } while (0)

#define FIN(bi, CON) do { \
        float mm = red[(0 * 64 + lane) * 17 + (bi) * 2 + wave]; \
        _Pragma("unroll") \
        for (int wv = 1; wv < 8; ++wv) \
            mm = fmaxf(mm, red[(wv * 64 + lane) * 17 + (bi) * 2 + wave]); \
        float v = rwc * (1.0f - mm); \
        v += __shfl_xor(v, 1, 64);  v += __shfl_xor(v, 2, 64); \
        v += __shfl_xor(v, 4, 64);  v += __shfl_xor(v, 8, 64); \
        v += __shfl_xor(v, 16, 64); v += __shfl_xor(v, 32, 64); \
        CON = v; } while (0)

    FINROUND(mA, mB, 0);     // waves 0,1 -> cA, cB sums
    FINROUND(mC, mD, 128);   // waves 0,1 -> cC, cD sums

#undef FIN
#undef FINROUND
}

// ---------- fallback (ws too small): naive but correct ----------
__global__ __launch_bounds__(256) void k_naive(const float* __restrict__ x0,
                                               const float* __restrict__ conj,
                                               const float* __restrict__ rw,
                                               float* __restrict__ out) {
    int b = blockIdx.x;
    int t = threadIdx.x;
    __shared__ float red[256];
    float acc = 0.0f;
    for (int c = t; c < C_; c += 256) {
        float mm = 0.0f;
        for (int v = 0; v < V_; ++v) {
            float mu1 = 1.0f / (1.0f + expf(-conj[(size_t)c * TWOV + v]));
            float mu2 = 1.0f / (1.0f + expf(-conj[(size_t)c * TWOV + V_ + v]));
            float x = x0[(size_t)b * V_ + v];
            mm = fmaxf(mm, fmaxf(mu1 * (1.0f - x), mu2 * x));
        }
        acc += rw[c] * (1.0f - mm);
    }
    red[t] = acc;
    __syncthreads();
    for (int s = 128; s > 0; s >>= 1) {
        if (t < s) red[t] += red[t + s];
        __syncthreads();
    }
    if (t == 0) out[b] = 5.0f + red[0];
}

extern "C" void kernel_launch(void* const* d_in, const int* in_sizes, int n_in,
                              void* d_out, int out_size, void* d_ws, size_t ws_size,
                              hipStream_t stream) {
    const float* x0   = (const float*)d_in[0];
    const float* conj = (const float*)d_in[1];
    const float* rw   = (const float*)d_in[2];
    float* out = (float*)d_out;

    const size_t need = (size_t)64 * C_ * 16;   // muH: 512 KB

    if (ws_size < need) {
        k_naive<<<B_, 256, 0, stream>>>(x0, conj, rw, out);
        return;
    }

    float4* muH = (float4*)d_ws;

    k_prep<<<64, 512, 0, stream>>>(conj, muH, out);
    dim3 grid(NBG, NCH);      // 128 x 2 = 256 blocks = 1/CU, 8 waves/CU
    k_main<<<grid, 512, 0, stream>>>(x0, muH, rw, out);
}

// Round 23
// 20.984 us; speedup vs baseline: 1.0668x; 1.0668x over previous
//
#include <hip/hip_runtime.h>

// RuleNet: out[b] = 5 + sum_c rw[c] * min_j( mu[c,j]*x[b,j] + (1-mu[c,j]) )
// x = [x0, 1-x0], mu = sigmoid(conjunctions).
// fit(b,c) = 1 - max_v max( mu1*(1-x0), mu2*x0 ).
//
// R23 = R21 (best: 20.96us; hand-lowered v_pk_mul_f16/v_pk_max_f16 core,
// 2 c/lane, 2 blocks/CU) with k_prep rebuilt for coalesced reads:
// block = c (512 blocks, 2 waves/CU), thread = vq -> two contiguous
// float4 reads per thread (1KB/wave coalesced), one 16B scattered write.
// R21's prep read at 2KB lane stride on 64 blocks (25% of chip).

#define B_    1024
#define C_    512
#define V_    256
#define TWOV  512

#define BPB    8               // batches per block
#define NBG    (B_ / BPB)      // 128 b-groups
#define NCH    4               // 4 chunks of 128 c (2 per lane: c, c+64)

typedef float    f32x4 __attribute__((ext_vector_type(4)));
typedef _Float16 h16x2 __attribute__((ext_vector_type(2)));

__device__ __forceinline__ float sigf(float z) {
    return 1.0f / (1.0f + __expf(-z));
}
__device__ __forceinline__ float packh2(float a, float b) {
    h16x2 h; h.x = (_Float16)a; h.y = (_Float16)b;
    return __builtin_bit_cast(float, h);
}

// packed f16 ops, hand-lowered (32-bit float carriers).
// R19/R20 lesson: _Float16 elementwise builtins mislower on ROCm 7.2;
// register-only VOP3P asm is regalloc-safe (unlike asm loads, R19).
#define PKMUL(D, A, Bq) asm("v_pk_mul_f16 %0, %1, %2" : "=v"(D) : "v"(A), "v"(Bq))
#define PKMAX(ACC, T)   asm("v_pk_max_f16 %0, %0, %1" : "+v"(ACC) : "v"(T))

// ---------- kernel 1: sigmoid -> f16 pack (coalesced reads), + out init ----
// muH[vq][c] : 16B = { m1(v0,v1), m1(v2,v3), m2(v0,v1), m2(v2,v3) } as f16 pairs
__global__ __launch_bounds__(64) void k_prep(const float* __restrict__ conj,
                                             float4* __restrict__ muH,
                                             float* __restrict__ out) {
    const int c  = blockIdx.x;       // 512 blocks = conjunctions
    const int vq = threadIdx.x;      // 64 threads = v-quads
    if (c < 16) out[c * 64 + vq] = 5.0f;
    const float* row = conj + (size_t)c * TWOV;
    // contiguous 16B per thread -> wave reads 1KB coalesced
    float4 a = *reinterpret_cast<const float4*>(row + vq * 4);        // mu1 src
    float4 b = *reinterpret_cast<const float4*>(row + V_ + vq * 4);   // mu2 src
    float4 r;
    r.x = packh2(sigf(a.x), sigf(a.y));
    r.y = packh2(sigf(a.z), sigf(a.w));
    r.z = packh2(sigf(b.x), sigf(b.y));
    r.w = packh2(sigf(b.z), sigf(b.w));
    muH[(size_t)vq * C_ + c] = r;    // 8KB-stride scatter (write-combined)
}

// ---------- kernel 2: main fuzzy-AND (hand-lowered packed f16) ----------
__global__ __launch_bounds__(512, 4) void k_main(const float* __restrict__ x0,
                                                 const float4* __restrict__ muH,
                                                 const float* __restrict__ rw,
                                                 float* __restrict__ out) {
    const int tid  = threadIdx.x;
    const int lane = tid & 63;
    const int wave = tid >> 6;                   // v-eighth owner (32 v = 8 vq)
    const int bg   = blockIdx.x;                 // 128 groups of 8 batches
    const int chunk= blockIdx.y;                 // 4 chunks of 128 c
    const int cA   = chunk * 128 + lane;         // lane's first c (cB = cA+64)
    const int vq0  = wave * 8;                   // this wave's vq base

    __shared__ float4 xs4[BPB * 64];             // 8 KB: [b][vq] {x01,x23,c01,c23}
    __shared__ float  red[8 * 64 * 17];          // 34 KB epilogue (stride 17)

    // stage x as f16 (x, 1-x) pairs; thread -> (b = tid>>6, vq = tid&63)
    {
        const int b = tid >> 6, vq = tid & 63;
        float4 xv = *reinterpret_cast<const float4*>(
            x0 + (size_t)(bg * BPB + b) * V_ + vq * 4);
        float4 pk;
        pk.x = packh2(xv.x, xv.y);               // x      (v0,v1)
        pk.y = packh2(xv.z, xv.w);               // x      (v2,v3)
        pk.z = packh2(1.0f - xv.x, 1.0f - xv.y); // (1-x)  (v0,v1)
        pk.w = packh2(1.0f - xv.z, 1.0f - xv.w); // (1-x)  (v2,v3)
        xs4[tid] = pk;
    }

    const float4* p = muH + (size_t)vq0 * C_ + cA;   // row q at p[q*C_]; cB at +64

    float accA[BPB], accB[BPB];                  // f16x2 carriers
#pragma unroll
    for (int i = 0; i < BPB; ++i) { accA[i] = 0.0f; accB[i] = 0.0f; }

    // prologue load (compiler-visible; it grades vmcnt itself)
    float4 MA = p[0];
    float4 MB = p[64];

    __syncthreads();                             // x tile ready

    // fuzzy-AND for batch bi: 16 pk instrs (2 c x 4 v), mul-only
#define PAIR(XC, bi, MAr, MBr) do { \
    float t0, t1, t2, t3; \
    PKMUL(t0, MAr.x, XC.z);   /* m1(v0,v1) * (1-x)(v0,v1)  [cA] */ \
    PKMUL(t1, MAr.z, XC.x);   /* m2(v0,v1) * x(v0,v1)      [cA] */ \
    PKMUL(t2, MAr.y, XC.w);   /* m1(v2,v3) * (1-x)(v2,v3)  [cA] */ \
    PKMUL(t3, MAr.w, XC.y);   /* m2(v2,v3) * x(v2,v3)      [cA] */ \
    PKMAX(accA[bi], t0); PKMAX(accA[bi], t1); \
    PKMAX(accA[bi], t2); PKMAX(accA[bi], t3); \
    PKMUL(t0, MBr.x, XC.z);   /* same for cB */ \
    PKMUL(t1, MBr.z, XC.x); \
    PKMUL(t2, MBr.y, XC.w); \
    PKMUL(t3, MBr.w, XC.y); \
    PKMAX(accB[bi], t0); PKMAX(accB[bi], t1); \
    PKMAX(accB[bi], t2); PKMAX(accB[bi], t3); \
    } while (0)

#pragma unroll
    for (int q = 0; q < 8; ++q) {
        // batch the 8 x ds_reads (independent, in flight together)
        float4 xc0 = xs4[0 * 64 + vq0 + q];
        float4 xc1 = xs4[1 * 64 + vq0 + q];
        float4 xc2 = xs4[2 * 64 + vq0 + q];
        float4 xc3 = xs4[3 * 64 + vq0 + q];
        float4 xc4 = xs4[4 * 64 + vq0 + q];
        float4 xc5 = xs4[5 * 64 + vq0 + q];
        float4 xc6 = xs4[6 * 64 + vq0 + q];
        float4 xc7 = xs4[7 * 64 + vq0 + q];
        // depth-1 prefetch of next row (compiler-visible)
        float4 NA, NB;
        if (q < 7) {
            NA = p[(size_t)(q + 1) * C_];
            NB = p[(size_t)(q + 1) * C_ + 64];
        }
        // pin current AFTER next's issue (R8-validated component pin)
        asm volatile("" : "+v"(MA.x), "+v"(MA.y), "+v"(MA.z), "+v"(MA.w),
                          "+v"(MB.x), "+v"(MB.y), "+v"(MB.z), "+v"(MB.w));
        PAIR(xc0, 0, MA, MB);
        PAIR(xc1, 1, MA, MB);
        PAIR(xc2, 2, MA, MB);
        PAIR(xc3, 3, MA, MB);
        PAIR(xc4, 4, MA, MB);
        PAIR(xc5, 5, MA, MB);
        PAIR(xc6, 6, MA, MB);
        PAIR(xc7, 7, MA, MB);
        if (q < 7) { MA = NA; MB = NB; }
    }
#undef PAIR

    // fold packed accumulators to f32 scalars (scalar cvt, outside hot loop)
    float mA[BPB], mB[BPB];
#pragma unroll
    for (int bi = 0; bi < BPB; ++bi) {
        h16x2 ha = __builtin_bit_cast(h16x2, accA[bi]);
        h16x2 hb = __builtin_bit_cast(h16x2, accB[bi]);
        mA[bi] = fmaxf((float)ha.x, (float)ha.y);
        mB[bi] = fmaxf((float)hb.x, (float)hb.y);
    }

    // ---- epilogue: combine 8 v-eighths, weight, sum over c, accumulate ----
#pragma unroll
    for (int bi = 0; bi < BPB; ++bi) {
        red[(wave * 64 + lane) * 17 + bi * 2 + 0] = mA[bi];
        red[(wave * 64 + lane) * 17 + bi * 2 + 1] = mB[bi];
    }
    __syncthreads();

    if (wave < 2) {                              // wave w finishes cc = w
        const float rwc = rw[chunk * 128 + wave * 64 + lane];
        float con0, con1, con2, con3, con4, con5, con6, con7;
#define FIN(bi, CON) do { \
        float mm = red[(0 * 64 + lane) * 17 + (bi) * 2 + wave]; \
        _Pragma("unroll") \
        for (int wv = 1; wv < 8; ++wv) \
            mm = fmaxf(mm, red[(wv * 64 + lane) * 17 + (bi) * 2 + wave]); \
        float v = rwc * (1.0f - mm); \
        v += __shfl_xor(v, 1, 64);  v += __shfl_xor(v, 2, 64); \
        v += __shfl_xor(v, 4, 64);  v += __shfl_xor(v, 8, 64); \
        v += __shfl_xor(v, 16, 64); v += __shfl_xor(v, 32, 64); \
        CON = v; } while (0)
        FIN(0, con0); FIN(1, con1); FIN(2, con2); FIN(3, con3);
        FIN(4, con4); FIN(5, con5); FIN(6, con6); FIN(7, con7);
#undef FIN
        float t0 = (lane & 1) ? con1 : con0;
        float t1 = (lane & 1) ? con3 : con2;
        float t2 = (lane & 1) ? con5 : con4;
        float t3 = (lane & 1) ? con7 : con6;
        float u0 = (lane & 2) ? t1 : t0;
        float u1 = (lane & 2) ? t3 : t2;
        float sel = (lane & 4) ? u1 : u0;
        if (lane < 8)
            atomicAdd(&out[bg * BPB + lane], sel);   // 8 adds/element total
    }
}

// ---------- fallback (ws too small): naive but correct ----------
__global__ __launch_bounds__(256) void k_naive(const float* __restrict__ x0,
                                               const float* __restrict__ conj,
                                               const float* __restrict__ rw,
                                               float* __restrict__ out) {
    int b = blockIdx.x;
    int t = threadIdx.x;
    __shared__ float red[256];
    float acc = 0.0f;
    for (int c = t; c < C_; c += 256) {
        float mm = 0.0f;
        for (int v = 0; v < V_; ++v) {
            float mu1 = 1.0f / (1.0f + expf(-conj[(size_t)c * TWOV + v]));
            float mu2 = 1.0f / (1.0f + expf(-conj[(size_t)c * TWOV + V_ + v]));
            float x = x0[(size_t)b * V_ + v];
            mm = fmaxf(mm, fmaxf(mu1 * (1.0f - x), mu2 * x));
        }
        acc += rw[c] * (1.0f - mm);
    }
    red[t] = acc;
    __syncthreads();
    for (int s = 128; s > 0; s >>= 1) {
        if (t < s) red[t] += red[t + s];
        __syncthreads();
    }
    if (t == 0) out[b] = 5.0f + red[0];
}

extern "C" void kernel_launch(void* const* d_in, const int* in_sizes, int n_in,
                              void* d_out, int out_size, void* d_ws, size_t ws_size,
                              hipStream_t stream) {
    const float* x0   = (const float*)d_in[0];
    const float* conj = (const float*)d_in[1];
    const float* rw   = (const float*)d_in[2];
    float* out = (float*)d_out;

    const size_t need = (size_t)64 * C_ * 16;   // muH: 512 KB

    if (ws_size < need) {
        k_naive<<<B_, 256, 0, stream>>>(x0, conj, rw, out);
        return;
    }

    float4* muH = (float4*)d_ws;

    k_prep<<<C_, 64, 0, stream>>>(conj, muH, out);
    dim3 grid(NBG, NCH);      // 128 x 4 = 512 blocks = 2/CU, 16 waves/CU
    k_main<<<grid, 512, 0, stream>>>(x0, muH, rw, out);
}